// Round 12
// baseline (144.649 us; speedup 1.0000x reference)
//
#include <hip/hip_runtime.h>
#include <hip/hip_fp16.h>

// CSPN: affinity conv -> 8 a-planes fp16 AoS (16 B/px) -> 24 diffusion steps,
// T=6 fused/launch. 64x32 tiles; each thread owns TWO vertically adjacent
// 4-px groups (rows xi, xi+1) -> middle-row taps come from registers, LDS
// ops/px cut ~40%. K packed fp16 in regs (K0 recomputed fp32).
constexpr int B = 8, H = 512, W = 512;
constexpr int N = B * H * W;
constexpr int HW = H * W;

constexpr int TTR = 64, TTC = 32;   // tile rows x cols
constexpr int T = 6;                // fused steps (24 = 4*6)
constexpr int XRR = TTR + 2 * T;    // 76 region rows
constexpr int XCC = TTC + 2 * T;    // 44 region cols
constexpr int XE = XRR * XCC;       // 3344 floats per buffer
constexpr int NG = XCC / 4;         // 11 col groups
constexpr int NPR = (XRR - 2) / 2;  // 37 row pairs (rows 1..74)
constexpr int NACT = NPR * NG;      // 407 active threads
constexpr int NTH = H / TTR, NTW = W / TTC;  // 8 x 16
constexpr int NTILES = B * NTH * NTW;        // 1024 (div 8 -> bijective swz)
constexpr int NT = 512;

// ---------------------------------------------------------------------------
// Kernel 1: affinity conv (1->8, 3x3 SAME) + bias -> normalize -> fp16 AoS.
// ---------------------------------------------------------------------------
__global__ __launch_bounds__(256) void cspn_gen_kernel(
    const float* __restrict__ x, const float* __restrict__ Wa,
    const float* __restrict__ ba, __half* __restrict__ Kh) {
  int idx = blockIdx.x * 256 + threadIdx.x;
  if (idx >= N) return;
  int j = idx & (W - 1);
  int i = (idx >> 9) & (H - 1);
  const float* xb = x + (idx & ~(HW - 1));

  float v[9];
#pragma unroll
  for (int u = 0; u < 3; ++u) {
#pragma unroll
    for (int t = 0; t < 3; ++t) {
      int ii = i + u - 1, jj = j + t - 1;
      v[u * 3 + t] = (unsigned(ii) < (unsigned)H && unsigned(jj) < (unsigned)W)
                         ? xb[ii * W + jj]
                         : 0.0f;
    }
  }

  float aff[8];
  float abs_sum = 0.0f;
#pragma unroll
  for (int c = 0; c < 8; ++c) {
    float a = ba[c];
#pragma unroll
    for (int t = 0; t < 9; ++t) a += v[t] * Wa[c * 9 + t];
    aff[c] = a;
    abs_sum += fabsf(a);
  }
  float inv = 1.0f / abs_sum;
#pragma unroll
  for (int c = 0; c < 8; ++c) aff[c] *= inv;

  union { uint4 u; __half2 h[4]; } pk;
#pragma unroll
  for (int c = 0; c < 4; ++c)
    pk.h[c] = __floats2half2_rn(aff[2 * c], aff[2 * c + 1]);
  *reinterpret_cast<uint4*>(Kh + (size_t)idx * 8) = pk.u;
}

// ---------------------------------------------------------------------------
// Kernel 2 helpers
// ---------------------------------------------------------------------------
#define H2F(h) __half2float(h)

struct KFrag {
  __half2 h[4][4];  // [px][tap-pair] (a1,a2)(a3,a4)(a5,a6)(a7,a8)
  float4 k0;        // fp32 center tap
};

__device__ __forceinline__ void load_kfrag(const __half* __restrict__ Kh,
                                           int b, int gi, int gj0, bool act,
                                           KFrag& f) {
  bool rowv = act && (unsigned)gi < (unsigned)H;
  const __half* Kb = Kh + ((size_t)b * HW + (size_t)(rowv ? gi : 0) * W) * 8;
  float k0v[4];
#pragma unroll
  for (int p = 0; p < 4; ++p) {
    int gj = gj0 + p;
    union { uint4 u; __half2 h[4]; } pk;
    pk.u = make_uint4(0u, 0u, 0u, 0u);
    if (rowv && (unsigned)gj < (unsigned)W)
      pk.u = *reinterpret_cast<const uint4*>(Kb + (size_t)gj * 8);
    float2 f01 = __half22float2(pk.h[0]);
    float2 f23 = __half22float2(pk.h[1]);
    float2 f45 = __half22float2(pk.h[2]);
    float2 f67 = __half22float2(pk.h[3]);
    k0v[p] = 1.0f - (f01.x + f01.y + f23.x + f23.y +
                     f45.x + f45.y + f67.x + f67.y);
    f.h[p][0] = pk.h[0]; f.h[p][1] = pk.h[1];
    f.h[p][2] = pk.h[2]; f.h[p][3] = pk.h[3];
  }
  f.k0 = make_float4(k0v[0], k0v[1], k0v[2], k0v[3]);
}

// 4-px stencil: u/c/d = up/center/down rows; l*/r* = col-edge scalars.
__device__ __forceinline__ float4 stencil4(const KFrag& f,
                                           float4 u, float lu, float ru,
                                           float4 c, float lc, float rc,
                                           float4 d, float ld, float rd) {
  float4 acc;
  acc.x = f.k0.x * c.x
        + H2F(f.h[0][0].x) * lc  + H2F(f.h[0][0].y) * c.y
        + H2F(f.h[0][1].x) * u.x + H2F(f.h[0][1].y) * lu
        + H2F(f.h[0][2].x) * u.y + H2F(f.h[0][2].y) * d.x
        + H2F(f.h[0][3].x) * ld  + H2F(f.h[0][3].y) * d.y;
  acc.y = f.k0.y * c.y
        + H2F(f.h[1][0].x) * c.x + H2F(f.h[1][0].y) * c.z
        + H2F(f.h[1][1].x) * u.y + H2F(f.h[1][1].y) * u.x
        + H2F(f.h[1][2].x) * u.z + H2F(f.h[1][2].y) * d.y
        + H2F(f.h[1][3].x) * d.x + H2F(f.h[1][3].y) * d.z;
  acc.z = f.k0.z * c.z
        + H2F(f.h[2][0].x) * c.y + H2F(f.h[2][0].y) * c.w
        + H2F(f.h[2][1].x) * u.z + H2F(f.h[2][1].y) * u.y
        + H2F(f.h[2][2].x) * u.w + H2F(f.h[2][2].y) * d.z
        + H2F(f.h[2][3].x) * d.y + H2F(f.h[2][3].y) * d.w;
  acc.w = f.k0.w * c.w
        + H2F(f.h[3][0].x) * c.z + H2F(f.h[3][0].y) * rc
        + H2F(f.h[3][1].x) * u.w + H2F(f.h[3][1].y) * u.z
        + H2F(f.h[3][2].x) * ru  + H2F(f.h[3][2].y) * d.w
        + H2F(f.h[3][3].x) * d.z + H2F(f.h[3][3].y) * rd;
  return acc;
}

// ---------------------------------------------------------------------------
// Kernel 2: T=6 fused steps, 64x32 tile, region 76x44 double-buffered.
// Thread owns rows xi,xi+1 x cols xj0..xj0+3 (8 px) for all steps.
// valid(s) = rows [s,75-s] x cols [s,43-s]; valid(6) = the tile exactly.
// ---------------------------------------------------------------------------
__global__ __launch_bounds__(NT, 4) void cspn_fused(
    const float* __restrict__ xin, const __half* __restrict__ Kh,
    float* __restrict__ xout) {
  __shared__ __align__(16) float sBuf[64 + 2 * XE + 64];  // front/back guards
  float* sX = sBuf + 64;

  int bid = blockIdx.x;
  int wg = (bid & 7) * (NTILES / 8) + (bid >> 3);  // XCD-chunked swizzle
  int b  = wg / (NTH * NTW);
  int rr = wg % (NTH * NTW);
  int ti0 = (rr / NTW) * TTR, tj0 = (rr % NTW) * TTC;
  int tid = threadIdx.x;

  bool active = tid < NACT;
  int pr  = tid / NG;              // 0..36
  int g   = tid - pr * NG;         // 0..10
  int xi  = 1 + 2 * pr;            // 1,3,...,73
  int xj0 = 4 * g;                 // 0..40

  // ---- one-time K fragments for both owned rows ----
  KFrag kA, kB;
  {
    int gia = ti0 + xi - T;
    int gj0 = tj0 + xj0 - T;
    load_kfrag(Kh, b, gia, gj0, active, kA);
    load_kfrag(Kh, b, gia + 1, gj0, active, kB);
  }

  // ---- safety: zero buf1 rows 0 and 75 (never computed, read at odd s) ----
  if (tid < 2 * XCC) {
    int r = (tid < XCC) ? 0 : (XRR - 1);
    int c = (tid < XCC) ? tid : tid - XCC;
    sX[XE + r * XCC + c] = 0.f;
  }

  // ---- stage X region into buf0 (float2) ----
  const float* xb = xin + (size_t)b * HW;
  for (int p = tid; p < XRR * (XCC / 2); p += NT) {   // 1672 float2
    int li = p / (XCC / 2), gc = p - li * (XCC / 2);
    int gi = ti0 + li - T, gj = tj0 + 2 * gc - T;
    float2 v = make_float2(0.f, 0.f);
    if ((unsigned)gi < (unsigned)H && (unsigned)gj < (unsigned)W)
      v = *reinterpret_cast<const float2*>(xb + gi * W + gj);
    *reinterpret_cast<float2*>(sX + li * XCC + 2 * gc) = v;
  }
  __syncthreads();

  // ---- T fused steps; own 8 px live in c1a/c1b ----
  int base_a = xi * XCC + xj0;
  int base_b = base_a + XCC;
  float4 c1a, c1b;
  if (active) {
    c1a = *reinterpret_cast<const float4*>(sX + base_a);
    c1b = *reinterpret_cast<const float4*>(sX + base_b);
  }
#pragma unroll
  for (int s = 0; s < T; ++s) {
    const float* Xc = sX + (s & 1) * XE;
    float* Xn = sX + (((s & 1) ^ 1)) * XE;
    if (active) {
      // neighbor rows from LDS
      float4 c0 = *reinterpret_cast<const float4*>(Xc + base_a - XCC);
      float4 c3 = *reinterpret_cast<const float4*>(Xc + base_b + XCC);
      // edge pairs: single base, offsets 0 and 5 (ds_read2-friendly)
      const float* em = Xc + base_a - XCC - 1;
      const float* ea = Xc + base_a - 1;
      const float* eb = Xc + base_b - 1;
      const float* ep = Xc + base_b + XCC - 1;
      float lm = em[0], rm = em[5];
      float la = ea[0], ra = ea[5];
      float lb = eb[0], rb = eb[5];
      float lp = ep[0], rp = ep[5];

      float4 acc_a = stencil4(kA, c0, lm, rm, c1a, la, ra, c1b, lb, rb);
      float4 acc_b = stencil4(kB, c1a, la, ra, c1b, lb, rb, c3, lp, rp);
      *reinterpret_cast<float4*>(Xn + base_a) = acc_a;
      *reinterpret_cast<float4*>(Xn + base_b) = acc_b;
      c1a = acc_a;
      c1b = acc_b;
    }
    __syncthreads();
  }

  // ---- write 64x32 tile (buf0; T even). 512 thr x 4 px ----
  {
    float* yb = xout + (size_t)b * HW;
    int i  = tid >> 3;              // 0..63
    int cg = tid & 7;               // 0..7 (float4 group)
    const float* e = sX + (T + i) * XCC + (T + 4 * cg);  // 8B-aligned
    float2 v0 = *reinterpret_cast<const float2*>(e);
    float2 v1 = *reinterpret_cast<const float2*>(e + 2);
    float4 v = make_float4(v0.x, v0.y, v1.x, v1.y);
    *reinterpret_cast<float4*>(yb + (size_t)(ti0 + i) * W + (tj0 + 4 * cg)) = v;
  }
}

extern "C" void kernel_launch(void* const* d_in, const int* in_sizes, int n_in,
                              void* d_out, int out_size, void* d_ws,
                              size_t ws_size, hipStream_t stream) {
  const float* x  = (const float*)d_in[0];
  const float* Wa = (const float*)d_in[1];
  const float* ba = (const float*)d_in[2];
  float* out = (float*)d_out;

  __half* Kh = (__half*)d_ws;                   // 8N halves = 33.5 MB
  float* xa = (float*)d_ws + 4 * (size_t)N;     // after 16N bytes
  cspn_gen_kernel<<<dim3(N / 256), dim3(256), 0, stream>>>(x, Wa, ba, Kh);

  const float* src = x;
  for (int l = 0; l < 24 / T; ++l) {   // 4 launches of 6 fused steps
    float* dst = (l & 1) ? out : xa;   // l=3 (odd) -> final lands in d_out
    cspn_fused<<<dim3(NTILES), dim3(NT), 0, stream>>>(src, Kh, dst);
    src = dst;
  }
}